// Round 5
// baseline (1052.935 us; speedup 1.0000x reference)
//
#include <hip/hip_runtime.h>
#include <hip/hip_bf16.h>
#include <cstdint>

// ---------------------------------------------------------------------------
// Problem constants
// ---------------------------------------------------------------------------
#define B_   4
#define T_   8192
#define D_   128
#define M_   8
#define BT_  (B_*T_)          // 32768 tokens
#define NC_  256              // scan chunks (32 steps each)
#define LCH_ (T_/NC_)         // 32 steps/chunk
#define Z_OFF (BT_*D_)        // d_out: [y (BT*D)] [z (BT*D)]

// workspace layout (bytes)
#define WS_PI    256
#define WS_W12   (WS_PI  + BT_*M_*4)        // 128x1024 bf16
#define WS_W2    (WS_W12 + 128*1024*2)      // 128x2048 bf16
#define WS_S     (WS_W2  + 128*2048*2)      // chunk end-states
#define WS_ZST   (WS_S   + NC_*B_*64*2*4)   // chunk start-states
// total ~2.8 MB

typedef float f32x4 __attribute__((ext_vector_type(4)));
typedef short short8 __attribute__((ext_vector_type(8)));

__device__ __forceinline__ unsigned short f2bf(float f){
  union { float f; uint32_t u; } v; v.f = f;
  return (unsigned short)((v.u + 0x7FFFu + ((v.u >> 16) & 1u)) >> 16);
}
__device__ __forceinline__ uint32_t pk2bf(float a, float b){
  return (uint32_t)f2bf(a) | ((uint32_t)f2bf(b) << 16);
}
__device__ __forceinline__ float bflo(uint32_t p){ return __int_as_float((int)(p << 16)); }
__device__ __forceinline__ float bfhi(uint32_t p){ return __int_as_float((int)(p & 0xffff0000u)); }
__device__ __forceinline__ float sigmoidf_(float x){ return 1.0f/(1.0f + __expf(-x)); }
__device__ __forceinline__ float scale_from(const float* s8){
  float s = 1.0f;
  #pragma unroll
  for (int m=0;m<M_;m++) s = fmaxf(s, s8[m]);
  return s;
}
// butterfly add over lane bits 0,1 via DPP quad_perm (VALU-only, no DS)
__device__ __forceinline__ float dpp_red4(float x){
  x += __int_as_float(__builtin_amdgcn_mov_dpp(__float_as_int(x), 0xB1, 0xF, 0xF, 1)); // xor 1
  x += __int_as_float(__builtin_amdgcn_mov_dpp(__float_as_int(x), 0x4E, 0xF, 0xF, 1)); // xor 2
  return x;
}

// ---------------------------------------------------------------------------
// K1: gate softmax pi + weight packing (bf16)
// ---------------------------------------------------------------------------
__global__ void prep_kernel(const float* __restrict__ u,
                            const float* __restrict__ gate_w,
                            const float* __restrict__ gate_b,
                            const float* __restrict__ K12,
                            const float* __restrict__ K21,
                            const float* __restrict__ K22,
                            float* __restrict__ pi_out,
                            unsigned short* __restrict__ w12,
                            unsigned short* __restrict__ w2)
{
  int bid = blockIdx.x;
  if (bid < BT_/4) {
    int wid = threadIdx.x >> 6, lane = threadIdx.x & 63;
    int bt = bid*4 + wid;
    float2 u2 = *(const float2*)(u + bt*D_ + lane*2);
    float lg[M_];
    #pragma unroll
    for (int m=0;m<M_;m++){
      float2 g2 = *(const float2*)(gate_w + m*D_ + lane*2);
      lg[m] = u2.x*g2.x + u2.y*g2.y;
    }
    #pragma unroll
    for (int off=32; off>=1; off>>=1){
      #pragma unroll
      for (int m=0;m<M_;m++) lg[m] += __shfl_xor(lg[m], off);
    }
    #pragma unroll
    for (int m=0;m<M_;m++) lg[m] += gate_b[m];
    float mx = lg[0];
    #pragma unroll
    for (int m=1;m<M_;m++) mx = fmaxf(mx, lg[m]);
    float e[M_]; float s = 0.f;
    #pragma unroll
    for (int m=0;m<M_;m++){ e[m] = __expf(lg[m]-mx); s += e[m]; }
    float inv = 1.0f/s;
    if (lane == 0){
      float* po = pi_out + bt*M_;
      *(float4*)(po)   = make_float4(e[0]*inv,e[1]*inv,e[2]*inv,e[3]*inv);
      *(float4*)(po+4) = make_float4(e[4]*inv,e[5]*inv,e[6]*inv,e[7]*inv);
    }
  } else {
    int idx = (bid - BT_/4)*1024 + threadIdx.x*4;
    #pragma unroll
    for (int t=0;t<4;t++){
      int i = idx + t;
      if (i < 128*1024){                   // W12[s, m*128+u] = K12[m,s,u]
        int s_ = i >> 10, kk = i & 1023;
        int mm = kk >> 7, uu = kk & 127;
        w12[i] = f2bf(K12[(mm*D_ + s_)*D_ + uu]);
      } else {                             // W2[y, kk]: kk<1024 -> K22, else K21
        int j = i - 128*1024;
        int y_ = j >> 11, kk = j & 2047;
        float val;
        if (kk < 1024){ int mm = kk>>7, uu = kk&127; val = K22[(mm*D_ + y_)*D_ + uu]; }
        else { int kk2 = kk-1024; int mm = kk2>>7, ss = kk2&127; val = K21[(mm*D_ + y_)*D_ + ss]; }
        w2[j] = f2bf(val);
      }
    }
  }
}

// ---------------------------------------------------------------------------
// K2: sigma_max per expert via shifted power iteration on B = K^T K.
// 1024 threads.  Thread (rg=tid>>2, cg=tid&3) owns row rg x cols 64*cg..+63.
// rowp = K row, bf16-packed [32] (32 regs); colk = K^T row, bf16-packed [32]
// (32 regs).  ALL register-array indexing is compile-time (rule #20: a single
// runtime store index demotes the whole array to scratch -- r4's 753us bug).
// Demand ~95 regs < the 128 grant tier -> no spill.  Iterations run in bf16;
// final sigma = ||K x|| recomputed against fp32 K from global.
// ---------------------------------------------------------------------------
#define SIG_IT 128
// x/y vectors: 64 float4 units, padded 16B every 8 units -> conflict-free b128
__device__ __forceinline__ int padf_(int unit){ return unit*4 + (unit>>3)*4; }

__global__ __launch_bounds__(1024, 4) void sigma_kernel(
    const float* __restrict__ rho_raw, const float* __restrict__ theta,
    const float* __restrict__ K12, const float* __restrict__ K21,
    const float* __restrict__ K22, float* __restrict__ sig_out)
{
  __shared__ float xv[304], yv[304];
  __shared__ float red[1];
  const int m   = blockIdx.x;
  const int tid = threadIdx.x;
  const int rg  = tid >> 2;      // 0..255 : row index
  const int cg  = tid & 3;       // 0..3   : 64-col group
  const int c0  = cg*64;
  const bool rlow = (rg < 128), clow = (c0 < 128);

  // rotation params for this row's pair (only valid when rlow)
  float rc=0.f, rs=0.f;
  if (rlow){
    int q = rg >> 1;
    float rho = sigmoidf_(rho_raw[q]) * 0.999f;
    rc = rho*cosf(theta[q]);  rs = rho*sinf(theta[q]);
  }
  const int q  = rg >> 1;
  // K11 row rg entries: col 2q -> v0, col 2q+1 -> v1
  const float v0 = (rg&1)? rs : rc;
  const float v1 = (rg&1)? rc : -rs;
  // K11 column rg entries (K^T row rg): row 2q -> e0, row 2q+1 -> e1
  const float e0 = (rg&1)? -rs : rc;
  const float e1 = (rg&1)?  rc : rs;

  // fp32 row base in global for the non-K11 part (also used for final matvec)
  const float* rbase = nullptr;
  if (rlow && !clow)       rbase = K12 + (m*128 + rg)*128       + (c0 - 128);
  else if (!rlow && clow)  rbase = K21 + (m*128 + (rg-128))*128 + c0;
  else if (!rlow && !clow) rbase = K22 + (m*128 + (rg-128))*128 + (c0 - 128);

  // ---- rowp[j] = pack_bf16( K[rg][c0+2j], K[rg][c0+2j+1] )   (32 regs)
  uint32_t rowp[32];
  if (rlow && clow) {
    #pragma unroll
    for (int j=0;j<32;j++)
      rowp[j] = (cg*32 + j == q) ? pk2bf(v0, v1) : 0u;   // static idx, cond value
  } else {
    #pragma unroll
    for (int j4=0;j4<16;j4++){
      float4 v = *(const float4*)(rbase + j4*4);
      rowp[2*j4+0] = pk2bf(v.x, v.y);
      rowp[2*j4+1] = pk2bf(v.z, v.w);
    }
  }

  // ---- colk[k] = pack_bf16( K[c0+2k][rg], K[c0+2k+1][rg] )   (32 regs)
  uint32_t colk[32];
  if (rlow && clow){
    #pragma unroll
    for (int k=0;k<32;k++)
      colk[k] = (cg*32 + k == q) ? pk2bf(e0, e1) : 0u;   // static idx, cond value
  } else {
    const float* base2; int ridx;
    if (clow && !rlow)      { base2 = K12 + m*128*128; ridx = rg - 128; }
    else if (!clow && rlow) { base2 = K21 + m*128*128; ridx = rg; }
    else                    { base2 = K22 + m*128*128; ridx = rg - 128; }
    int abase = clow ? c0 : c0 - 128;
    #pragma unroll
    for (int k=0;k<32;k++){
      int a = abase + 2*k;
      float f0 = base2[a*128 + ridx];
      float f1 = base2[(a+1)*128 + ridx];
      colk[k] = pk2bf(f0, f1);
    }
  }

  // ---- init x (unnormalized)
  if (tid < 256)
    xv[padf_(tid>>2) + (tid&3)] = 1.0f + 0.25f*__sinf(0.731f*(float)tid);
  __syncthreads();

  const int xu = padf_(rg>>2) + (rg&3);   // this row's slot in xv/yv
  float cshift = 0.0f;
  for (int it=0; it<SIG_IT; ++it){
    // phase 1: y = K x   (bf16 rowp)
    float py = 0.f;
    #pragma unroll
    for (int j4=0;j4<16;j4++){
      float4 x4 = *(const float4*)&xv[padf_(cg*16 + j4)];
      uint32_t p0 = rowp[2*j4], p1 = rowp[2*j4+1];
      py = fmaf(bflo(p0), x4.x, py);
      py = fmaf(bfhi(p0), x4.y, py);
      py = fmaf(bflo(p1), x4.z, py);
      py = fmaf(bfhi(p1), x4.w, py);
    }
    py = dpp_red4(py);
    if (cg == 0) yv[xu] = py;
    __syncthreads();
    // phase 2: x' = K^T y - cshift*x   (bf16 colk)
    float px = 0.f;
    #pragma unroll
    for (int k4=0;k4<16;k4++){
      float4 y4 = *(const float4*)&yv[padf_(cg*16 + k4)];
      uint32_t p0 = colk[2*k4], p1 = colk[2*k4+1];
      px = fmaf(bflo(p0), y4.x, px);
      px = fmaf(bfhi(p0), y4.y, px);
      px = fmaf(bflo(p1), y4.z, px);
      px = fmaf(bfhi(p1), y4.w, px);
    }
    px = dpp_red4(px);
    if (cg == 0){
      float xo = xv[xu];
      xv[xu] = px - cshift*xo;
    }
    __syncthreads();
    // renormalize every 16 iters; set shift from norm growth at it==31
    if ((it & 15) == 15){
      float4 xx;
      if (tid < 64){
        xx = *(const float4*)&xv[padf_(tid)];
        float n2 = xx.x*xx.x + xx.y*xx.y + xx.z*xx.z + xx.w*xx.w;
        #pragma unroll
        for (int off=32; off>=1; off>>=1) n2 += __shfl_xor(n2, off);
        if (tid == 0) red[0] = n2;
      }
      __syncthreads();
      float n2 = red[0];
      if (it == 31) cshift = 0.45f * (cshift + exp2f(log2f(n2) * (1.0f/32.0f)));
      if (tid < 64){
        float inv = rsqrtf(n2);
        *(float4*)&xv[padf_(tid)] = make_float4(xx.x*inv, xx.y*inv, xx.z*inv, xx.w*inv);
      }
      __syncthreads();
    }
  }
  // final: sigma = ||K x|| with fp32 K (K11 synthesized; rest re-read global)
  {
    float py = 0.f;
    if (rlow && clow){
      if (2*q >= c0 && 2*q < c0+64){
        float xa = xv[padf_((2*q)>>2)   + ((2*q)&3)];
        float xb = xv[padf_((2*q+1)>>2) + ((2*q+1)&3)];
        py = v0*xa + v1*xb;
      }
    } else {
      #pragma unroll
      for (int j4=0;j4<16;j4++){
        float4 kv = *(const float4*)(rbase + j4*4);
        float4 x4 = *(const float4*)&xv[padf_(cg*16 + j4)];
        py = fmaf(kv.x, x4.x, py);
        py = fmaf(kv.y, x4.y, py);
        py = fmaf(kv.z, x4.z, py);
        py = fmaf(kv.w, x4.w, py);
      }
    }
    py = dpp_red4(py);
    if (cg == 0) yv[xu] = py;
    __syncthreads();
    if (tid < 64){
      float4 yy = *(const float4*)&yv[padf_(tid)];
      float n2 = yy.x*yy.x + yy.y*yy.y + yy.z*yy.z + yy.w*yy.w;
      #pragma unroll
      for (int off=32; off>=1; off>>=1) n2 += __shfl_xor(n2, off);
      if (tid == 0) sig_out[m] = sqrtf(n2);
    }
  }
}

// ---------------------------------------------------------------------------
// GEMM: out[32768x128] = A[32768xKTOT] * Wpack^T, A built on the fly:
//   kk < 1024 : A[bt,kk] = pi[bt, kk>>7] * u[bt, kk&127]
//   kk >= 1024: A[bt,kk] = pi[bt,(kk-1024)>>7] * z[bt,(kk-1024)&127]
// epilogue scales by 1/scale.  128x128 tile, 4 waves, mfma 16x16x32 bf16.
// ---------------------------------------------------------------------------
template<int KTOT, bool SECOND>
__global__ __launch_bounds__(256) void gemm_kernel(
    const float* __restrict__ u, const float* __restrict__ zsrc,
    const float* __restrict__ pi, const unsigned short* __restrict__ wpack,
    float* __restrict__ out, const float* __restrict__ sig8)
{
  float inv_s = 1.0f / scale_from(sig8);
  __shared__ unsigned short a_lds[128*64];
  __shared__ unsigned short b_lds[128*64];
  const int tid  = threadIdx.x;
  const int lane = tid & 63;
  const int wid  = tid >> 6;
  const int wr   = wid >> 1, wc = wid & 1;
  const int bt0  = blockIdx.x * 128;
  f32x4 acc[4][4];
  #pragma unroll
  for (int a=0;a<4;a++){
    #pragma unroll
    for (int b=0;b<4;b++) acc[a][b] = (f32x4){0.f,0.f,0.f,0.f};
  }
  const int r = tid >> 1, half = tid & 1;
  for (int kk0 = 0; kk0 < KTOT; kk0 += 64){
    { // A-stage (reg-staged: fp32 load, *pi, ->bf16)
      const float* src; int mm, j0;
      if (!SECOND || kk0 < 1024){ mm = kk0 >> 7; j0 = (kk0 & 127) + half*32; src = u + (bt0+r)*D_ + j0; }
      else { int k2 = kk0 - 1024; mm = k2 >> 7; j0 = (k2 & 127) + half*32; src = zsrc + (bt0+r)*D_ + j0; }
      float pv = pi[(bt0+r)*M_ + mm];
      unsigned short* dst = &a_lds[r*64 + half*32];
      #pragma unroll
      for (int i=0;i<8;i++){
        float4 v = *(const float4*)(src + i*4);
        ushort4 w;
        w.x=f2bf(v.x*pv); w.y=f2bf(v.y*pv); w.z=f2bf(v.z*pv); w.w=f2bf(v.w*pv);
        *(ushort4*)(dst + i*4) = w;
      }
      // B-stage (bf16 pack, N x K row-major = B^T layout)
      const unsigned short* srcb = wpack + r*KTOT + kk0 + half*32;
      uint4* dstb = (uint4*)&b_lds[r*64 + half*32];
      #pragma unroll
      for (int i=0;i<4;i++) dstb[i] = *(const uint4*)(srcb + i*8);
    }
    __syncthreads();
    #pragma unroll
    for (int ks=0; ks<2; ks++){
      short8 af[4], bfr[4];
      #pragma unroll
      for (int f=0; f<4; f++){
        int ar_ = wr*64 + f*16 + (lane&15);
        af[f]  = *(const short8*)&a_lds[ar_*64 + ks*32 + (lane>>4)*8];
        int bn  = wc*64 + f*16 + (lane&15);
        bfr[f] = *(const short8*)&b_lds[bn*64 + ks*32 + (lane>>4)*8];
      }
      #pragma unroll
      for (int fr=0; fr<4; fr++){
        #pragma unroll
        for (int fc=0; fc<4; fc++)
          acc[fr][fc] = __builtin_amdgcn_mfma_f32_16x16x32_bf16(af[fr], bfr[fc], acc[fr][fc], 0,0,0);
      }
    }
    __syncthreads();
  }
  #pragma unroll
  for (int fr=0; fr<4; fr++){
    #pragma unroll
    for (int fc=0; fc<4; fc++){
      #pragma unroll
      for (int rr=0; rr<4; rr++){
        int row = bt0 + wr*64 + fr*16 + (lane>>4)*4 + rr;
        int col = wc*64 + fc*16 + (lane&15);
        out[row*D_ + col] = acc[fr][fc][rr]*inv_s;
      }
    }
  }
}

// ---------------------------------------------------------------------------
// Scan: 256 independent complex recurrences (block-diag 2x2 rotations).
// 3-phase exact chunked scan, NC_=256 chunks of 32.  v is in the y-region of
// d_out (already /scale).  Reference emits carry BEFORE consuming v[t].
// ---------------------------------------------------------------------------
__global__ void scan_a(const float* __restrict__ v, const float* __restrict__ rho_raw,
                       const float* __restrict__ theta, const float* __restrict__ sig8,
                       float* __restrict__ Ssum)
{
  int b = blockIdx.x >> 8, c = blockIdx.x & 255;
  int p = threadIdx.x;
  float sc  = scale_from(sig8);
  float rho = sigmoidf_(rho_raw[p]) * 0.999f / sc;
  float th  = theta[p];
  float ar = rho*cosf(th), ai = rho*sinf(th);
  const float2* vp = (const float2*)v + (b*T_ + c*LCH_)*64 + p;
  float zx=0.f, zy=0.f;
  #pragma unroll 8
  for (int t=0; t<LCH_; ++t){
    float2 vt = vp[t*64];
    float nx = fmaf(ar, zx, fmaf(-ai, zy, vt.x));
    float ny = fmaf(ai, zx, fmaf( ar, zy, vt.y));
    zx = nx; zy = ny;
  }
  ((float2*)Ssum)[(b*NC_ + c)*64 + p] = make_float2(zx, zy);
}

__global__ void scan_b(const float* __restrict__ Ssum, float* __restrict__ Zst,
                       const float* __restrict__ rho_raw, const float* __restrict__ theta,
                       const float* __restrict__ sig8)
{
  int tid = threadIdx.x;          // 256 = B_*64
  int b = tid >> 6, p = tid & 63;
  float sc  = scale_from(sig8);
  float rho = sigmoidf_(rho_raw[p]) * 0.999f / sc;
  float th  = theta[p];
  float qr = rho*cosf(th), qi = rho*sinf(th);
  #pragma unroll
  for (int s=0;s<5;s++){ float nr = qr*qr - qi*qi; float ni = 2.f*qr*qi; qr=nr; qi=ni; } // a^32
  float Zx=0.f, Zy=0.f;
  const float2* S = (const float2*)Ssum;
  float2* Z = (float2*)Zst;
  #pragma unroll 4
  for (int c=0;c<NC_;c++){
    Z[(b*NC_+c)*64 + p] = make_float2(Zx, Zy);
    float2 s = S[(b*NC_+c)*64 + p];
    float nx = qr*Zx - qi*Zy + s.x;
    float ny = qi*Zx + qr*Zy + s.y;
    Zx = nx; Zy = ny;
  }
}

__global__ void scan_c(const float* __restrict__ v, const float* __restrict__ Zst,
                       const float* __restrict__ rho_raw, const float* __restrict__ theta,
                       const float* __restrict__ sig8, float* __restrict__ zout)
{
  int b = blockIdx.x >> 8, c = blockIdx.x & 255;
  int p = threadIdx.x;
  float sc  = scale_from(sig8);
  float rho = sigmoidf_(rho_raw[p]) * 0.999f / sc;
  float th  = theta[p];
  float ar = rho*cosf(th), ai = rho*sinf(th);
  const float2* vp = (const float2*)v + (b*T_ + c*LCH_)*64 + p;
  float2*       zp = (float2*)zout    + (b*T_ + c*LCH_)*64 + p;
  float2 z0 = ((const float2*)Zst)[(b*NC_+c)*64 + p];
  float zx = z0.x, zy = z0.y;
  #pragma unroll 8
  for (int t=0; t<LCH_; ++t){
    zp[t*64] = make_float2(zx, zy);      // emit BEFORE consuming v[t]
    float2 vt = vp[t*64];
    float nx = fmaf(ar, zx, fmaf(-ai, zy, vt.x));
    float ny = fmaf(ai, zx, fmaf( ar, zy, vt.y));
    zx = nx; zy = ny;
  }
}

// ---------------------------------------------------------------------------
extern "C" void kernel_launch(void* const* d_in, const int* in_sizes, int n_in,
                              void* d_out, int out_size, void* d_ws, size_t ws_size,
                              hipStream_t stream)
{
  const float* u       = (const float*)d_in[0];
  const float* rho_raw = (const float*)d_in[1];
  const float* theta   = (const float*)d_in[2];
  const float* K12     = (const float*)d_in[3];
  const float* K21     = (const float*)d_in[4];
  const float* K22     = (const float*)d_in[5];
  const float* gate_w  = (const float*)d_in[6];
  const float* gate_b  = (const float*)d_in[7];
  float* out = (float*)d_out;
  char*  ws  = (char*)d_ws;
  float* sig8 = (float*)ws;
  float* pi   = (float*)(ws + WS_PI);
  unsigned short* w12 = (unsigned short*)(ws + WS_W12);
  unsigned short* w2  = (unsigned short*)(ws + WS_W2);
  float* Ssum = (float*)(ws + WS_S);
  float* Zst  = (float*)(ws + WS_ZST);
  float* v    = out;            // y-region doubles as v scratch until GEMM2
  float* zout = out + Z_OFF;

  hipLaunchKernelGGL(sigma_kernel, dim3(8), dim3(1024), 0, stream,
                     rho_raw, theta, K12, K21, K22, sig8);
  hipLaunchKernelGGL(prep_kernel, dim3(BT_/4 + 384), dim3(256), 0, stream,
                     u, gate_w, gate_b, K12, K21, K22, pi, w12, w2);
  hipLaunchKernelGGL((gemm_kernel<1024,false>), dim3(256), dim3(256), 0, stream,
                     u, u, pi, w12, v, sig8);
  hipLaunchKernelGGL(scan_a, dim3(B_*NC_), dim3(64), 0, stream, v, rho_raw, theta, sig8, Ssum);
  hipLaunchKernelGGL(scan_b, dim3(1), dim3(256), 0, stream, Ssum, Zst, rho_raw, theta, sig8);
  hipLaunchKernelGGL(scan_c, dim3(B_*NC_), dim3(64), 0, stream, v, Zst, rho_raw, theta, sig8, zout);
  hipLaunchKernelGGL((gemm_kernel<2048,true>), dim3(256), dim3(256), 0, stream,
                     u, zout, pi, w2, out, sig8);
}

// Round 6
// 1049.896 us; speedup vs baseline: 1.0029x; 1.0029x over previous
//
#include <hip/hip_runtime.h>
#include <hip/hip_bf16.h>
#include <cstdint>

// ---------------------------------------------------------------------------
// Problem constants
// ---------------------------------------------------------------------------
#define B_   4
#define T_   8192
#define D_   128
#define M_   8
#define BT_  (B_*T_)          // 32768 tokens
#define NC_  256              // scan chunks (32 steps each)
#define LCH_ (T_/NC_)         // 32 steps/chunk
#define Z_OFF (BT_*D_)        // d_out: [y (BT*D)] [z (BT*D)]

// workspace layout (bytes)
#define WS_PI    256
#define WS_W12   (WS_PI  + BT_*M_*4)        // 128x1024 bf16
#define WS_W2    (WS_W12 + 128*1024*2)      // 128x2048 bf16
#define WS_S     (WS_W2  + 128*2048*2)      // chunk end-states
#define WS_ZST   (WS_S   + NC_*B_*64*2*4)   // chunk start-states
// total ~2.8 MB

typedef float f32x4 __attribute__((ext_vector_type(4)));
typedef short short8 __attribute__((ext_vector_type(8)));

__device__ __forceinline__ unsigned short f2bf(float f){
  union { float f; uint32_t u; } v; v.f = f;
  return (unsigned short)((v.u + 0x7FFFu + ((v.u >> 16) & 1u)) >> 16);
}
__device__ __forceinline__ uint32_t pk2bf(float a, float b){
  return (uint32_t)f2bf(a) | ((uint32_t)f2bf(b) << 16);
}
__device__ __forceinline__ float bflo(uint32_t p){ return __int_as_float((int)(p << 16)); }
__device__ __forceinline__ float bfhi(uint32_t p){ return __int_as_float((int)(p & 0xffff0000u)); }
__device__ __forceinline__ float sigmoidf_(float x){ return 1.0f/(1.0f + __expf(-x)); }
__device__ __forceinline__ float scale_from(const float* s8){
  float s = 1.0f;
  #pragma unroll
  for (int m=0;m<M_;m++) s = fmaxf(s, s8[m]);
  return s;
}
// butterfly add over lane bits 0,1 via DPP quad_perm (VALU-only, no DS)
__device__ __forceinline__ float dpp_red4(float x){
  x += __int_as_float(__builtin_amdgcn_mov_dpp(__float_as_int(x), 0xB1, 0xF, 0xF, 1)); // xor 1
  x += __int_as_float(__builtin_amdgcn_mov_dpp(__float_as_int(x), 0x4E, 0xF, 0xF, 1)); // xor 2
  return x;
}

// ---------------------------------------------------------------------------
// K1: gate softmax pi + weight packing (bf16)
// ---------------------------------------------------------------------------
__global__ void prep_kernel(const float* __restrict__ u,
                            const float* __restrict__ gate_w,
                            const float* __restrict__ gate_b,
                            const float* __restrict__ K12,
                            const float* __restrict__ K21,
                            const float* __restrict__ K22,
                            float* __restrict__ pi_out,
                            unsigned short* __restrict__ w12,
                            unsigned short* __restrict__ w2)
{
  int bid = blockIdx.x;
  if (bid < BT_/4) {
    int wid = threadIdx.x >> 6, lane = threadIdx.x & 63;
    int bt = bid*4 + wid;
    float2 u2 = *(const float2*)(u + bt*D_ + lane*2);
    float lg[M_];
    #pragma unroll
    for (int m=0;m<M_;m++){
      float2 g2 = *(const float2*)(gate_w + m*D_ + lane*2);
      lg[m] = u2.x*g2.x + u2.y*g2.y;
    }
    #pragma unroll
    for (int off=32; off>=1; off>>=1){
      #pragma unroll
      for (int m=0;m<M_;m++) lg[m] += __shfl_xor(lg[m], off);
    }
    #pragma unroll
    for (int m=0;m<M_;m++) lg[m] += gate_b[m];
    float mx = lg[0];
    #pragma unroll
    for (int m=1;m<M_;m++) mx = fmaxf(mx, lg[m]);
    float e[M_]; float s = 0.f;
    #pragma unroll
    for (int m=0;m<M_;m++){ e[m] = __expf(lg[m]-mx); s += e[m]; }
    float inv = 1.0f/s;
    if (lane == 0){
      float* po = pi_out + bt*M_;
      *(float4*)(po)   = make_float4(e[0]*inv,e[1]*inv,e[2]*inv,e[3]*inv);
      *(float4*)(po+4) = make_float4(e[4]*inv,e[5]*inv,e[6]*inv,e[7]*inv);
    }
  } else {
    int idx = (bid - BT_/4)*1024 + threadIdx.x*4;
    #pragma unroll
    for (int t=0;t<4;t++){
      int i = idx + t;
      if (i < 128*1024){                   // W12[s, m*128+u] = K12[m,s,u]
        int s_ = i >> 10, kk = i & 1023;
        int mm = kk >> 7, uu = kk & 127;
        w12[i] = f2bf(K12[(mm*D_ + s_)*D_ + uu]);
      } else {                             // W2[y, kk]: kk<1024 -> K22, else K21
        int j = i - 128*1024;
        int y_ = j >> 11, kk = j & 2047;
        float val;
        if (kk < 1024){ int mm = kk>>7, uu = kk&127; val = K22[(mm*D_ + y_)*D_ + uu]; }
        else { int kk2 = kk-1024; int mm = kk2>>7, ss = kk2&127; val = K21[(mm*D_ + y_)*D_ + ss]; }
        w2[j] = f2bf(val);
      }
    }
  }
}

// ---------------------------------------------------------------------------
// K2: sigma_max per expert via shifted power iteration on B = K^T K.
// 1024 threads.  Thread (rg=tid>>2, cg=tid&3) owns row rg x cols 64*cg..+63.
// rowp = K row bf16-packed [32]; colk = K^T row bf16-packed [32]; all static
// indexing (rule #20).  Demand ~95 VGPRs.  amdgpu_waves_per_eu(4,4) pins the
// allocator to 4 waves/SIMD = 128-VGPR budget (r4/r5: launch_bounds' 2nd arg
// acted as min-BLOCKS/CU -> 8 waves/SIMD target -> 64-reg grant -> spill).
// Iterations bf16; final sigma = ||K x|| against fp32 K.
// ---------------------------------------------------------------------------
#define SIG_IT 128
// x/y vectors: 64 float4 units, padded 16B every 8 units -> conflict-free b128
__device__ __forceinline__ int padf_(int unit){ return unit*4 + (unit>>3)*4; }

__global__ __launch_bounds__(1024)
__attribute__((amdgpu_waves_per_eu(4, 4)))
void sigma_kernel(
    const float* __restrict__ rho_raw, const float* __restrict__ theta,
    const float* __restrict__ K12, const float* __restrict__ K21,
    const float* __restrict__ K22, float* __restrict__ sig_out)
{
  __shared__ float xv[304], yv[304];
  __shared__ float red[1];
  const int m   = blockIdx.x;
  const int tid = threadIdx.x;
  const int rg  = tid >> 2;      // 0..255 : row index
  const int cg  = tid & 3;       // 0..3   : 64-col group
  const int c0  = cg*64;
  const bool rlow = (rg < 128), clow = (c0 < 128);

  // rotation params for this row's pair (only valid when rlow)
  float rc=0.f, rs=0.f;
  if (rlow){
    int q = rg >> 1;
    float rho = sigmoidf_(rho_raw[q]) * 0.999f;
    rc = rho*cosf(theta[q]);  rs = rho*sinf(theta[q]);
  }
  const int q  = rg >> 1;
  // K11 row rg entries: col 2q -> v0, col 2q+1 -> v1
  const float v0 = (rg&1)? rs : rc;
  const float v1 = (rg&1)? rc : -rs;
  // K11 column rg entries (K^T row rg): row 2q -> e0, row 2q+1 -> e1
  const float e0 = (rg&1)? -rs : rc;
  const float e1 = (rg&1)?  rc : rs;

  // fp32 row base in global for the non-K11 part (also used for final matvec)
  const float* rbase = nullptr;
  if (rlow && !clow)       rbase = K12 + (m*128 + rg)*128       + (c0 - 128);
  else if (!rlow && clow)  rbase = K21 + (m*128 + (rg-128))*128 + c0;
  else if (!rlow && !clow) rbase = K22 + (m*128 + (rg-128))*128 + (c0 - 128);

  // ---- rowp[j] = pack_bf16( K[rg][c0+2j], K[rg][c0+2j+1] )   (32 regs)
  uint32_t rowp[32];
  if (rlow && clow) {
    #pragma unroll
    for (int j=0;j<32;j++)
      rowp[j] = (cg*32 + j == q) ? pk2bf(v0, v1) : 0u;   // static idx, cond value
  } else {
    #pragma unroll
    for (int j4=0;j4<16;j4++){
      float4 v = *(const float4*)(rbase + j4*4);
      rowp[2*j4+0] = pk2bf(v.x, v.y);
      rowp[2*j4+1] = pk2bf(v.z, v.w);
    }
  }

  // ---- colk[k] = pack_bf16( K[c0+2k][rg], K[c0+2k+1][rg] )   (32 regs)
  uint32_t colk[32];
  if (rlow && clow){
    #pragma unroll
    for (int k=0;k<32;k++)
      colk[k] = (cg*32 + k == q) ? pk2bf(e0, e1) : 0u;   // static idx, cond value
  } else {
    const float* base2; int ridx;
    if (clow && !rlow)      { base2 = K12 + m*128*128; ridx = rg - 128; }
    else if (!clow && rlow) { base2 = K21 + m*128*128; ridx = rg; }
    else                    { base2 = K22 + m*128*128; ridx = rg - 128; }
    int abase = clow ? c0 : c0 - 128;
    #pragma unroll
    for (int k=0;k<32;k++){
      int a = abase + 2*k;
      float f0 = base2[a*128 + ridx];
      float f1 = base2[(a+1)*128 + ridx];
      colk[k] = pk2bf(f0, f1);
    }
  }

  // ---- init x (unnormalized)
  if (tid < 256)
    xv[padf_(tid>>2) + (tid&3)] = 1.0f + 0.25f*__sinf(0.731f*(float)tid);
  __syncthreads();

  const int xu = padf_(rg>>2) + (rg&3);   // this row's slot in xv/yv
  float cshift = 0.0f;
  for (int it=0; it<SIG_IT; ++it){
    // phase 1: y = K x   (bf16 rowp)
    float py = 0.f;
    #pragma unroll
    for (int j4=0;j4<16;j4++){
      float4 x4 = *(const float4*)&xv[padf_(cg*16 + j4)];
      uint32_t p0 = rowp[2*j4], p1 = rowp[2*j4+1];
      py = fmaf(bflo(p0), x4.x, py);
      py = fmaf(bfhi(p0), x4.y, py);
      py = fmaf(bflo(p1), x4.z, py);
      py = fmaf(bfhi(p1), x4.w, py);
    }
    py = dpp_red4(py);
    if (cg == 0) yv[xu] = py;
    __syncthreads();
    // phase 2: x' = K^T y - cshift*x   (bf16 colk)
    float px = 0.f;
    #pragma unroll
    for (int k4=0;k4<16;k4++){
      float4 y4 = *(const float4*)&yv[padf_(cg*16 + k4)];
      uint32_t p0 = colk[2*k4], p1 = colk[2*k4+1];
      px = fmaf(bflo(p0), y4.x, px);
      px = fmaf(bfhi(p0), y4.y, px);
      px = fmaf(bflo(p1), y4.z, px);
      px = fmaf(bfhi(p1), y4.w, px);
    }
    px = dpp_red4(px);
    if (cg == 0){
      float xo = xv[xu];
      xv[xu] = px - cshift*xo;
    }
    __syncthreads();
    // renormalize every 16 iters; set shift from norm growth at it==31
    if ((it & 15) == 15){
      float4 xx;
      if (tid < 64){
        xx = *(const float4*)&xv[padf_(tid)];
        float n2 = xx.x*xx.x + xx.y*xx.y + xx.z*xx.z + xx.w*xx.w;
        #pragma unroll
        for (int off=32; off>=1; off>>=1) n2 += __shfl_xor(n2, off);
        if (tid == 0) red[0] = n2;
      }
      __syncthreads();
      float n2 = red[0];
      if (it == 31) cshift = 0.45f * (cshift + exp2f(log2f(n2) * (1.0f/32.0f)));
      if (tid < 64){
        float inv = rsqrtf(n2);
        *(float4*)&xv[padf_(tid)] = make_float4(xx.x*inv, xx.y*inv, xx.z*inv, xx.w*inv);
      }
      __syncthreads();
    }
  }
  // final: sigma = ||K x|| with fp32 K (K11 synthesized; rest re-read global)
  {
    float py = 0.f;
    if (rlow && clow){
      if (2*q >= c0 && 2*q < c0+64){
        float xa = xv[padf_((2*q)>>2)   + ((2*q)&3)];
        float xb = xv[padf_((2*q+1)>>2) + ((2*q+1)&3)];
        py = v0*xa + v1*xb;
      }
    } else {
      #pragma unroll
      for (int j4=0;j4<16;j4++){
        float4 kv = *(const float4*)(rbase + j4*4);
        float4 x4 = *(const float4*)&xv[padf_(cg*16 + j4)];
        py = fmaf(kv.x, x4.x, py);
        py = fmaf(kv.y, x4.y, py);
        py = fmaf(kv.z, x4.z, py);
        py = fmaf(kv.w, x4.w, py);
      }
    }
    py = dpp_red4(py);
    if (cg == 0) yv[xu] = py;
    __syncthreads();
    if (tid < 64){
      float4 yy = *(const float4*)&yv[padf_(tid)];
      float n2 = yy.x*yy.x + yy.y*yy.y + yy.z*yy.z + yy.w*yy.w;
      #pragma unroll
      for (int off=32; off>=1; off>>=1) n2 += __shfl_xor(n2, off);
      if (tid == 0) sig_out[m] = sqrtf(n2);
    }
  }
}

// ---------------------------------------------------------------------------
// GEMM: out[32768x128] = A[32768xKTOT] * Wpack^T, A built on the fly:
//   kk < 1024 : A[bt,kk] = pi[bt, kk>>7] * u[bt, kk&127]
//   kk >= 1024: A[bt,kk] = pi[bt,(kk-1024)>>7] * z[bt,(kk-1024)&127]
// epilogue scales by 1/scale.  128x128 tile, 4 waves, mfma 16x16x32 bf16.
// ---------------------------------------------------------------------------
template<int KTOT, bool SECOND>
__global__ __launch_bounds__(256) void gemm_kernel(
    const float* __restrict__ u, const float* __restrict__ zsrc,
    const float* __restrict__ pi, const unsigned short* __restrict__ wpack,
    float* __restrict__ out, const float* __restrict__ sig8)
{
  float inv_s = 1.0f / scale_from(sig8);
  __shared__ unsigned short a_lds[128*64];
  __shared__ unsigned short b_lds[128*64];
  const int tid  = threadIdx.x;
  const int lane = tid & 63;
  const int wid  = tid >> 6;
  const int wr   = wid >> 1, wc = wid & 1;
  const int bt0  = blockIdx.x * 128;
  f32x4 acc[4][4];
  #pragma unroll
  for (int a=0;a<4;a++){
    #pragma unroll
    for (int b=0;b<4;b++) acc[a][b] = (f32x4){0.f,0.f,0.f,0.f};
  }
  const int r = tid >> 1, half = tid & 1;
  for (int kk0 = 0; kk0 < KTOT; kk0 += 64){
    { // A-stage (reg-staged: fp32 load, *pi, ->bf16)
      const float* src; int mm, j0;
      if (!SECOND || kk0 < 1024){ mm = kk0 >> 7; j0 = (kk0 & 127) + half*32; src = u + (bt0+r)*D_ + j0; }
      else { int k2 = kk0 - 1024; mm = k2 >> 7; j0 = (k2 & 127) + half*32; src = zsrc + (bt0+r)*D_ + j0; }
      float pv = pi[(bt0+r)*M_ + mm];
      unsigned short* dst = &a_lds[r*64 + half*32];
      #pragma unroll
      for (int i=0;i<8;i++){
        float4 v = *(const float4*)(src + i*4);
        ushort4 w;
        w.x=f2bf(v.x*pv); w.y=f2bf(v.y*pv); w.z=f2bf(v.z*pv); w.w=f2bf(v.w*pv);
        *(ushort4*)(dst + i*4) = w;
      }
      // B-stage (bf16 pack, N x K row-major = B^T layout)
      const unsigned short* srcb = wpack + r*KTOT + kk0 + half*32;
      uint4* dstb = (uint4*)&b_lds[r*64 + half*32];
      #pragma unroll
      for (int i=0;i<4;i++) dstb[i] = *(const uint4*)(srcb + i*8);
    }
    __syncthreads();
    #pragma unroll
    for (int ks=0; ks<2; ks++){
      short8 af[4], bfr[4];
      #pragma unroll
      for (int f=0; f<4; f++){
        int ar_ = wr*64 + f*16 + (lane&15);
        af[f]  = *(const short8*)&a_lds[ar_*64 + ks*32 + (lane>>4)*8];
        int bn  = wc*64 + f*16 + (lane&15);
        bfr[f] = *(const short8*)&b_lds[bn*64 + ks*32 + (lane>>4)*8];
      }
      #pragma unroll
      for (int fr=0; fr<4; fr++){
        #pragma unroll
        for (int fc=0; fc<4; fc++)
          acc[fr][fc] = __builtin_amdgcn_mfma_f32_16x16x32_bf16(af[fr], bfr[fc], acc[fr][fc], 0,0,0);
      }
    }
    __syncthreads();
  }
  #pragma unroll
  for (int fr=0; fr<4; fr++){
    #pragma unroll
    for (int fc=0; fc<4; fc++){
      #pragma unroll
      for (int rr=0; rr<4; rr++){
        int row = bt0 + wr*64 + fr*16 + (lane>>4)*4 + rr;
        int col = wc*64 + fc*16 + (lane&15);
        out[row*D_ + col] = acc[fr][fc][rr]*inv_s;
      }
    }
  }
}

// ---------------------------------------------------------------------------
// Scan: 256 independent complex recurrences (block-diag 2x2 rotations).
// 3-phase exact chunked scan, NC_=256 chunks of 32.  v is in the y-region of
// d_out (already /scale).  Reference emits carry BEFORE consuming v[t].
// ---------------------------------------------------------------------------
__global__ void scan_a(const float* __restrict__ v, const float* __restrict__ rho_raw,
                       const float* __restrict__ theta, const float* __restrict__ sig8,
                       float* __restrict__ Ssum)
{
  int b = blockIdx.x >> 8, c = blockIdx.x & 255;
  int p = threadIdx.x;
  float sc  = scale_from(sig8);
  float rho = sigmoidf_(rho_raw[p]) * 0.999f / sc;
  float th  = theta[p];
  float ar = rho*cosf(th), ai = rho*sinf(th);
  const float2* vp = (const float2*)v + (b*T_ + c*LCH_)*64 + p;
  float zx=0.f, zy=0.f;
  #pragma unroll 8
  for (int t=0; t<LCH_; ++t){
    float2 vt = vp[t*64];
    float nx = fmaf(ar, zx, fmaf(-ai, zy, vt.x));
    float ny = fmaf(ai, zx, fmaf( ar, zy, vt.y));
    zx = nx; zy = ny;
  }
  ((float2*)Ssum)[(b*NC_ + c)*64 + p] = make_float2(zx, zy);
}

__global__ void scan_b(const float* __restrict__ Ssum, float* __restrict__ Zst,
                       const float* __restrict__ rho_raw, const float* __restrict__ theta,
                       const float* __restrict__ sig8)
{
  int tid = threadIdx.x;          // 256 = B_*64
  int b = tid >> 6, p = tid & 63;
  float sc  = scale_from(sig8);
  float rho = sigmoidf_(rho_raw[p]) * 0.999f / sc;
  float th  = theta[p];
  float qr = rho*cosf(th), qi = rho*sinf(th);
  #pragma unroll
  for (int s=0;s<5;s++){ float nr = qr*qr - qi*qi; float ni = 2.f*qr*qi; qr=nr; qi=ni; } // a^32
  float Zx=0.f, Zy=0.f;
  const float2* S = (const float2*)Ssum;
  float2* Z = (float2*)Zst;
  #pragma unroll 4
  for (int c=0;c<NC_;c++){
    Z[(b*NC_+c)*64 + p] = make_float2(Zx, Zy);
    float2 s = S[(b*NC_+c)*64 + p];
    float nx = qr*Zx - qi*Zy + s.x;
    float ny = qi*Zx + qr*Zy + s.y;
    Zx = nx; Zy = ny;
  }
}

__global__ void scan_c(const float* __restrict__ v, const float* __restrict__ Zst,
                       const float* __restrict__ rho_raw, const float* __restrict__ theta,
                       const float* __restrict__ sig8, float* __restrict__ zout)
{
  int b = blockIdx.x >> 8, c = blockIdx.x & 255;
  int p = threadIdx.x;
  float sc  = scale_from(sig8);
  float rho = sigmoidf_(rho_raw[p]) * 0.999f / sc;
  float th  = theta[p];
  float ar = rho*cosf(th), ai = rho*sinf(th);
  const float2* vp = (const float2*)v + (b*T_ + c*LCH_)*64 + p;
  float2*       zp = (float2*)zout    + (b*T_ + c*LCH_)*64 + p;
  float2 z0 = ((const float2*)Zst)[(b*NC_+c)*64 + p];
  float zx = z0.x, zy = z0.y;
  #pragma unroll 8
  for (int t=0; t<LCH_; ++t){
    zp[t*64] = make_float2(zx, zy);      // emit BEFORE consuming v[t]
    float2 vt = vp[t*64];
    float nx = fmaf(ar, zx, fmaf(-ai, zy, vt.x));
    float ny = fmaf(ai, zx, fmaf( ar, zy, vt.y));
    zx = nx; zy = ny;
  }
}

// ---------------------------------------------------------------------------
extern "C" void kernel_launch(void* const* d_in, const int* in_sizes, int n_in,
                              void* d_out, int out_size, void* d_ws, size_t ws_size,
                              hipStream_t stream)
{
  const float* u       = (const float*)d_in[0];
  const float* rho_raw = (const float*)d_in[1];
  const float* theta   = (const float*)d_in[2];
  const float* K12     = (const float*)d_in[3];
  const float* K21     = (const float*)d_in[4];
  const float* K22     = (const float*)d_in[5];
  const float* gate_w  = (const float*)d_in[6];
  const float* gate_b  = (const float*)d_in[7];
  float* out = (float*)d_out;
  char*  ws  = (char*)d_ws;
  float* sig8 = (float*)ws;
  float* pi   = (float*)(ws + WS_PI);
  unsigned short* w12 = (unsigned short*)(ws + WS_W12);
  unsigned short* w2  = (unsigned short*)(ws + WS_W2);
  float* Ssum = (float*)(ws + WS_S);
  float* Zst  = (float*)(ws + WS_ZST);
  float* v    = out;            // y-region doubles as v scratch until GEMM2
  float* zout = out + Z_OFF;

  hipLaunchKernelGGL(sigma_kernel, dim3(8), dim3(1024), 0, stream,
                     rho_raw, theta, K12, K21, K22, sig8);
  hipLaunchKernelGGL(prep_kernel, dim3(BT_/4 + 384), dim3(256), 0, stream,
                     u, gate_w, gate_b, K12, K21, K22, pi, w12, w2);
  hipLaunchKernelGGL((gemm_kernel<1024,false>), dim3(256), dim3(256), 0, stream,
                     u, u, pi, w12, v, sig8);
  hipLaunchKernelGGL(scan_a, dim3(B_*NC_), dim3(64), 0, stream, v, rho_raw, theta, sig8, Ssum);
  hipLaunchKernelGGL(scan_b, dim3(1), dim3(256), 0, stream, Ssum, Zst, rho_raw, theta, sig8);
  hipLaunchKernelGGL(scan_c, dim3(B_*NC_), dim3(64), 0, stream, v, Zst, rho_raw, theta, sig8, zout);
  hipLaunchKernelGGL((gemm_kernel<2048,true>), dim3(256), dim3(256), 0, stream,
                     u, zout, pi, w2, out, sig8);
}

// Round 8
// 664.479 us; speedup vs baseline: 1.5846x; 1.5800x over previous
//
#include <hip/hip_runtime.h>
#include <hip/hip_bf16.h>
#include <cstdint>

// ---------------------------------------------------------------------------
// Problem constants
// ---------------------------------------------------------------------------
#define B_   4
#define T_   8192
#define D_   128
#define M_   8
#define BT_  (B_*T_)          // 32768 tokens
#define NC_  256              // scan chunks (32 steps each)
#define LCH_ (T_/NC_)         // 32 steps/chunk
#define Z_OFF (BT_*D_)        // d_out: [y (BT*D)] [z (BT*D)]

// workspace layout (bytes)
#define WS_PI    256
#define WS_W12   (WS_PI  + BT_*M_*4)        // 128x1024 bf16
#define WS_W2    (WS_W12 + 128*1024*2)      // 128x2048 bf16
#define WS_S     (WS_W2  + 128*2048*2)      // chunk end-states
#define WS_ZST   (WS_S   + NC_*B_*64*2*4)   // chunk start-states
// total ~2.8 MB

typedef float f32x4 __attribute__((ext_vector_type(4)));
typedef short short8 __attribute__((ext_vector_type(8)));

__device__ __forceinline__ unsigned short f2bf(float f){
  union { float f; uint32_t u; } v; v.f = f;
  return (unsigned short)((v.u + 0x7FFFu + ((v.u >> 16) & 1u)) >> 16);
}
__device__ __forceinline__ uint32_t pk2bf(float a, float b){
  return (uint32_t)f2bf(a) | ((uint32_t)f2bf(b) << 16);
}
__device__ __forceinline__ float bflo(uint32_t p){ return __int_as_float((int)(p << 16)); }
__device__ __forceinline__ float bfhi(uint32_t p){ return __int_as_float((int)(p & 0xffff0000u)); }
__device__ __forceinline__ float sigmoidf_(float x){ return 1.0f/(1.0f + __expf(-x)); }
__device__ __forceinline__ float scale_from(const float* s8){
  float s = 1.0f;
  #pragma unroll
  for (int m=0;m<M_;m++) s = fmaxf(s, s8[m]);
  return s;
}
// butterfly add over lane bits 0..3 (16-lane groups)
__device__ __forceinline__ float red16(float x){
  x += __shfl_xor(x, 1);
  x += __shfl_xor(x, 2);
  x += __shfl_xor(x, 4);
  x += __shfl_xor(x, 8);
  return x;
}

// ---------------------------------------------------------------------------
// K1: gate softmax pi + weight packing (bf16)
// ---------------------------------------------------------------------------
__global__ void prep_kernel(const float* __restrict__ u,
                            const float* __restrict__ gate_w,
                            const float* __restrict__ gate_b,
                            const float* __restrict__ K12,
                            const float* __restrict__ K21,
                            const float* __restrict__ K22,
                            float* __restrict__ pi_out,
                            unsigned short* __restrict__ w12,
                            unsigned short* __restrict__ w2)
{
  int bid = blockIdx.x;
  if (bid < BT_/4) {
    int wid = threadIdx.x >> 6, lane = threadIdx.x & 63;
    int bt = bid*4 + wid;
    float2 u2 = *(const float2*)(u + bt*D_ + lane*2);
    float lg[M_];
    #pragma unroll
    for (int m=0;m<M_;m++){
      float2 g2 = *(const float2*)(gate_w + m*D_ + lane*2);
      lg[m] = u2.x*g2.x + u2.y*g2.y;
    }
    #pragma unroll
    for (int off=32; off>=1; off>>=1){
      #pragma unroll
      for (int m=0;m<M_;m++) lg[m] += __shfl_xor(lg[m], off);
    }
    #pragma unroll
    for (int m=0;m<M_;m++) lg[m] += gate_b[m];
    float mx = lg[0];
    #pragma unroll
    for (int m=1;m<M_;m++) mx = fmaxf(mx, lg[m]);
    float e[M_]; float s = 0.f;
    #pragma unroll
    for (int m=0;m<M_;m++){ e[m] = __expf(lg[m]-mx); s += e[m]; }
    float inv = 1.0f/s;
    if (lane == 0){
      float* po = pi_out + bt*M_;
      *(float4*)(po)   = make_float4(e[0]*inv,e[1]*inv,e[2]*inv,e[3]*inv);
      *(float4*)(po+4) = make_float4(e[4]*inv,e[5]*inv,e[6]*inv,e[7]*inv);
    }
  } else {
    int idx = (bid - BT_/4)*1024 + threadIdx.x*4;
    #pragma unroll
    for (int t=0;t<4;t++){
      int i = idx + t;
      if (i < 128*1024){                   // W12[s, m*128+u] = K12[m,s,u]
        int s_ = i >> 10, kk = i & 1023;
        int mm = kk >> 7, uu = kk & 127;
        w12[i] = f2bf(K12[(mm*D_ + s_)*D_ + uu]);
      } else {                             // W2[y, kk]: kk<1024 -> K22, else K21
        int j = i - 128*1024;
        int y_ = j >> 11, kk = j & 2047;
        float val;
        if (kk < 1024){ int mm = kk>>7, uu = kk&127; val = K22[(mm*D_ + y_)*D_ + uu]; }
        else { int kk2 = kk-1024; int mm = kk2>>7, ss = kk2&127; val = K21[(mm*D_ + y_)*D_ + ss]; }
        w2[j] = f2bf(val);
      }
    }
  }
}

// ---------------------------------------------------------------------------
// K2: sigma_max per expert via shifted power iteration on B = K^T K.
// 512 threads (empirical VGPR grant = 65536/block = 128).  Thread
// (a=tid>>4, cg=tid&15) owns rows {a+32i, i=0..7} x cols [16cg, 16cg+16):
//   rowp[64] = K rows bf16-packed (64 regs)  -> phase 1 (y = Kx) reg-resident.
//   KlT in LDS [256 cols][130 dwords pad]    -> phase 2 (x' = K^T y) reads
//   K^T rows CONTIGUOUSLY (aligned ds_read_b64), no stride-129 column pokes.
// Demand ~105 regs < 128 grant -> no spill (r2-r6 all spilled: demand>grant).
// All register-array indexing compile-time (rule #20).  Iterations bf16;
// final sigma = ||K x|| against fp32 K from global.
// ---------------------------------------------------------------------------
#define SIG_IT 128
// x/y vectors: 64 float4 units, padded 16B every 8 units
__device__ __forceinline__ int padf_(int unit){ return unit*4 + (unit>>3)*4; }

__global__ __launch_bounds__(512) void sigma_kernel(
    const float* __restrict__ rho_raw, const float* __restrict__ theta,
    const float* __restrict__ K12, const float* __restrict__ K21,
    const float* __restrict__ K22, float* __restrict__ sig_out)
{
  __shared__ uint32_t KlT[256*130];    // 133120 B: row c, dword d = K[2d][c],K[2d+1][c]
  __shared__ float xv[304], yv[304];
  __shared__ float red[1];
  const int m   = blockIdx.x;
  const int tid = threadIdx.x;
  const int a_  = tid >> 4;      // 0..31 : row-set {a_+32i}
  const int cg  = tid & 15;      // 0..15 : 16-col window
  const int c0  = cg*16;
  const bool clow = (c0 < 128);

  // ---- rowp[8i+d] = pack_bf16( K[a_+32i][c0+2d], K[a_+32i][c0+2d+1] )
  uint32_t rowp[64];
  #pragma unroll
  for (int i=0;i<8;i++){
    const int row = a_ + 32*i;
    if (row < 128 && clow){
      // K11: row's pair q -> cols 2q,2q+1
      const int qi = row >> 1;
      float rho = sigmoidf_(rho_raw[qi]) * 0.999f;
      float rcv = rho*cosf(theta[qi]), rsv = rho*sinf(theta[qi]);
      float w0 = (row&1)? rsv : rcv;
      float w1 = (row&1)? rcv : -rsv;
      uint32_t pv = pk2bf(w0, w1);
      const bool inwin = ((qi >> 3) == cg);
      #pragma unroll
      for (int d=0; d<8; ++d)
        rowp[8*i+d] = (inwin && d == (qi & 7)) ? pv : 0u;
    } else {
      const float* rb;
      if (row < 128)     rb = K12 + (m*128 + row)*128       + (c0 - 128);
      else if (clow)     rb = K21 + (m*128 + (row-128))*128 + c0;
      else               rb = K22 + (m*128 + (row-128))*128 + (c0 - 128);
      #pragma unroll
      for (int j=0;j<4;j++){
        float4 v = *(const float4*)(rb + 4*j);
        rowp[8*i+2*j]   = pk2bf(v.x, v.y);
        rowp[8*i+2*j+1] = pk2bf(v.z, v.w);
      }
    }
  }

  // ---- scatter K^T into LDS: KlT[c][dw] halves via ds_write_b16
  {
    unsigned short* KlTh = (unsigned short*)KlT;
    #pragma unroll
    for (int i=0;i<8;i++){
      const int dw = (a_ >> 1) + 16*i;           // (a_+32i)>>1
      #pragma unroll
      for (int jj=0; jj<16; ++jj){
        const int c = c0 + jj;
        uint32_t pv = rowp[8*i + (jj>>1)];
        unsigned short h = (jj&1) ? (unsigned short)(pv >> 16)
                                  : (unsigned short)(pv & 0xffffu);
        KlTh[(c*130 + dw)*2 + (a_ & 1)] = h;
      }
    }
  }
  // ---- init x
  if (tid < 256)
    xv[padf_(tid>>2) + (tid&3)] = 1.0f + 0.25f*__sinf(0.731f*(float)tid);
  __syncthreads();

  float cshift = 0.0f;
  for (int it=0; it<SIG_IT; ++it){
    // phase 1: y = K x  (rowp regs; x broadcast reads)
    float4 xq0 = *(const float4*)&xv[padf_(4*cg+0)];
    float4 xq1 = *(const float4*)&xv[padf_(4*cg+1)];
    float4 xq2 = *(const float4*)&xv[padf_(4*cg+2)];
    float4 xq3 = *(const float4*)&xv[padf_(4*cg+3)];
    float py[8];
    #pragma unroll
    for (int i=0;i<8;i++){
      float acc = 0.f;
      uint32_t p0 = rowp[8*i+0], p1 = rowp[8*i+1];
      acc = fmaf(bflo(p0), xq0.x, acc); acc = fmaf(bfhi(p0), xq0.y, acc);
      acc = fmaf(bflo(p1), xq0.z, acc); acc = fmaf(bfhi(p1), xq0.w, acc);
      p0 = rowp[8*i+2]; p1 = rowp[8*i+3];
      acc = fmaf(bflo(p0), xq1.x, acc); acc = fmaf(bfhi(p0), xq1.y, acc);
      acc = fmaf(bflo(p1), xq1.z, acc); acc = fmaf(bfhi(p1), xq1.w, acc);
      p0 = rowp[8*i+4]; p1 = rowp[8*i+5];
      acc = fmaf(bflo(p0), xq2.x, acc); acc = fmaf(bfhi(p0), xq2.y, acc);
      acc = fmaf(bflo(p1), xq2.z, acc); acc = fmaf(bfhi(p1), xq2.w, acc);
      p0 = rowp[8*i+6]; p1 = rowp[8*i+7];
      acc = fmaf(bflo(p0), xq3.x, acc); acc = fmaf(bfhi(p0), xq3.y, acc);
      acc = fmaf(bflo(p1), xq3.z, acc); acc = fmaf(bfhi(p1), xq3.w, acc);
      py[i] = red16(acc);
    }
    if (cg == 0){
      #pragma unroll
      for (int i=0;i<8;i++)
        yv[padf_((a_>>2) + 8*i) + (a_&3)] = py[i];
    }
    __syncthreads();
    // phase 2: x' = K^T y - cshift*x  (KlT rows contiguous b64; y broadcast)
    float4 yq0 = *(const float4*)&yv[padf_(4*cg+0)];
    float4 yq1 = *(const float4*)&yv[padf_(4*cg+1)];
    float4 yq2 = *(const float4*)&yv[padf_(4*cg+2)];
    float4 yq3 = *(const float4*)&yv[padf_(4*cg+3)];
    float px[8];
    #pragma unroll
    for (int i=0;i<8;i++){
      const int c = a_ + 32*i;
      const uint32_t* kr = &KlT[c*130 + 8*cg];
      float acc = 0.f;
      #pragma unroll
      for (int d2=0; d2<4; ++d2){
        const int dd = (d2 + (cg>>2)) & 3;       // rotate to spread banks
        uint2 kp = *(const uint2*)&kr[2*dd];
        float4 yq = (dd==0)? yq0 : (dd==1)? yq1 : (dd==2)? yq2 : yq3;
        acc = fmaf(bflo(kp.x), yq.x, acc);
        acc = fmaf(bfhi(kp.x), yq.y, acc);
        acc = fmaf(bflo(kp.y), yq.z, acc);
        acc = fmaf(bfhi(kp.y), yq.w, acc);
      }
      px[i] = red16(acc);
    }
    __syncthreads();
    if (cg == 0){
      #pragma unroll
      for (int i=0;i<8;i++){
        const int c = a_ + 32*i;
        const int slot = padf_(c>>2) + (c&3);
        float xo = xv[slot];
        xv[slot] = px[i] - cshift*xo;
      }
    }
    __syncthreads();
    // renormalize every 16 iters; set shift from norm growth at it==31
    if ((it & 15) == 15){
      float4 xx;
      if (tid < 64){
        xx = *(const float4*)&xv[padf_(tid)];
        float n2 = xx.x*xx.x + xx.y*xx.y + xx.z*xx.z + xx.w*xx.w;
        #pragma unroll
        for (int off=32; off>=1; off>>=1) n2 += __shfl_xor(n2, off);
        if (tid == 0) red[0] = n2;
      }
      __syncthreads();
      float n2 = red[0];
      if (it == 31) cshift = 0.45f * (cshift + exp2f(log2f(n2) * (1.0f/32.0f)));
      if (tid < 64){
        float inv = rsqrtf(n2);
        *(float4*)&xv[padf_(tid)] = make_float4(xx.x*inv, xx.y*inv, xx.z*inv, xx.w*inv);
      }
      __syncthreads();
    }
  }
  // ---- final: sigma = ||K x|| with fp32 K (K11 synth; rest from global)
  {
    float4 xq0 = *(const float4*)&xv[padf_(4*cg+0)];
    float4 xq1 = *(const float4*)&xv[padf_(4*cg+1)];
    float4 xq2 = *(const float4*)&xv[padf_(4*cg+2)];
    float4 xq3 = *(const float4*)&xv[padf_(4*cg+3)];
    float pys[8];
    #pragma unroll
    for (int i=0;i<8;i++){
      const int row = a_ + 32*i;
      float acc = 0.f;
      if (row < 128 && clow){
        const int qi = row >> 1;
        if ((qi >> 3) == cg){
          float rho = sigmoidf_(rho_raw[qi]) * 0.999f;
          float rcv = rho*cosf(theta[qi]), rsv = rho*sinf(theta[qi]);
          float w0 = (row&1)? rsv : rcv;
          float w1 = (row&1)? rcv : -rsv;
          float xa = xv[padf_(qi>>1) + 2*(qi&1)];
          float xb = xv[padf_(qi>>1) + 2*(qi&1) + 1];
          acc = w0*xa + w1*xb;
        }
      } else {
        const float* rb;
        if (row < 128)     rb = K12 + (m*128 + row)*128       + (c0 - 128);
        else if (clow)     rb = K21 + (m*128 + (row-128))*128 + c0;
        else               rb = K22 + (m*128 + (row-128))*128 + (c0 - 128);
        float4 k0 = *(const float4*)(rb + 0);
        float4 k1 = *(const float4*)(rb + 4);
        float4 k2 = *(const float4*)(rb + 8);
        float4 k3 = *(const float4*)(rb + 12);
        acc = fmaf(k0.x, xq0.x, acc); acc = fmaf(k0.y, xq0.y, acc);
        acc = fmaf(k0.z, xq0.z, acc); acc = fmaf(k0.w, xq0.w, acc);
        acc = fmaf(k1.x, xq1.x, acc); acc = fmaf(k1.y, xq1.y, acc);
        acc = fmaf(k1.z, xq1.z, acc); acc = fmaf(k1.w, xq1.w, acc);
        acc = fmaf(k2.x, xq2.x, acc); acc = fmaf(k2.y, xq2.y, acc);
        acc = fmaf(k2.z, xq2.z, acc); acc = fmaf(k2.w, xq2.w, acc);
        acc = fmaf(k3.x, xq3.x, acc); acc = fmaf(k3.y, xq3.y, acc);
        acc = fmaf(k3.z, xq3.z, acc); acc = fmaf(k3.w, xq3.w, acc);
      }
      pys[i] = red16(acc);
    }
    if (cg == 0){
      #pragma unroll
      for (int i=0;i<8;i++)
        yv[padf_((a_>>2) + 8*i) + (a_&3)] = pys[i];
    }
    __syncthreads();
    if (tid < 64){
      float4 yy = *(const float4*)&yv[padf_(tid)];
      float n2 = yy.x*yy.x + yy.y*yy.y + yy.z*yy.z + yy.w*yy.w;
      #pragma unroll
      for (int off=32; off>=1; off>>=1) n2 += __shfl_xor(n2, off);
      if (tid == 0) sig_out[m] = sqrtf(n2);
    }
  }
}

// ---------------------------------------------------------------------------
// GEMM: out[32768x128] = A[32768xKTOT] * Wpack^T, A built on the fly:
//   kk < 1024 : A[bt,kk] = pi[bt, kk>>7] * u[bt, kk&127]
//   kk >= 1024: A[bt,kk] = pi[bt,(kk-1024)>>7] * z[bt,(kk-1024)&127]
// epilogue scales by 1/scale.  128x128 tile, 4 waves, mfma 16x16x32 bf16.
// ---------------------------------------------------------------------------
template<int KTOT, bool SECOND>
__global__ __launch_bounds__(256) void gemm_kernel(
    const float* __restrict__ u, const float* __restrict__ zsrc,
    const float* __restrict__ pi, const unsigned short* __restrict__ wpack,
    float* __restrict__ out, const float* __restrict__ sig8)
{
  float inv_s = 1.0f / scale_from(sig8);
  __shared__ unsigned short a_lds[128*64];
  __shared__ unsigned short b_lds[128*64];
  const int tid  = threadIdx.x;
  const int lane = tid & 63;
  const int wid  = tid >> 6;
  const int wr   = wid >> 1, wc = wid & 1;
  const int bt0  = blockIdx.x * 128;
  f32x4 acc[4][4];
  #pragma unroll
  for (int a=0;a<4;a++){
    #pragma unroll
    for (int b=0;b<4;b++) acc[a][b] = (f32x4){0.f,0.f,0.f,0.f};
  }
  const int r = tid >> 1, half = tid & 1;
  for (int kk0 = 0; kk0 < KTOT; kk0 += 64){
    { // A-stage (reg-staged: fp32 load, *pi, ->bf16)
      const float* src; int mm, j0;
      if (!SECOND || kk0 < 1024){ mm = kk0 >> 7; j0 = (kk0 & 127) + half*32; src = u + (bt0+r)*D_ + j0; }
      else { int k2 = kk0 - 1024; mm = k2 >> 7; j0 = (k2 & 127) + half*32; src = zsrc + (bt0+r)*D_ + j0; }
      float pv = pi[(bt0+r)*M_ + mm];
      unsigned short* dst = &a_lds[r*64 + half*32];
      #pragma unroll
      for (int i=0;i<8;i++){
        float4 v = *(const float4*)(src + i*4);
        ushort4 w;
        w.x=f2bf(v.x*pv); w.y=f2bf(v.y*pv); w.z=f2bf(v.z*pv); w.w=f2bf(v.w*pv);
        *(ushort4*)(dst + i*4) = w;
      }
      // B-stage (bf16 pack, N x K row-major = B^T layout)
      const unsigned short* srcb = wpack + r*KTOT + kk0 + half*32;
      uint4* dstb = (uint4*)&b_lds[r*64 + half*32];
      #pragma unroll
      for (int i=0;i<4;i++) dstb[i] = *(const uint4*)(srcb + i*8);
    }
    __syncthreads();
    #pragma unroll
    for (int ks=0; ks<2; ks++){
      short8 af[4], bfr[4];
      #pragma unroll
      for (int f=0; f<4; f++){
        int ar_ = wr*64 + f*16 + (lane&15);
        af[f]  = *(const short8*)&a_lds[ar_*64 + ks*32 + (lane>>4)*8];
        int bn  = wc*64 + f*16 + (lane&15);
        bfr[f] = *(const short8*)&b_lds[bn*64 + ks*32 + (lane>>4)*8];
      }
      #pragma unroll
      for (int fr=0; fr<4; fr++){
        #pragma unroll
        for (int fc=0; fc<4; fc++)
          acc[fr][fc] = __builtin_amdgcn_mfma_f32_16x16x32_bf16(af[fr], bfr[fc], acc[fr][fc], 0,0,0);
      }
    }
    __syncthreads();
  }
  #pragma unroll
  for (int fr=0; fr<4; fr++){
    #pragma unroll
    for (int fc=0; fc<4; fc++){
      #pragma unroll
      for (int rr=0; rr<4; rr++){
        int row = bt0 + wr*64 + fr*16 + (lane>>4)*4 + rr;
        int col = wc*64 + fc*16 + (lane&15);
        out[row*D_ + col] = acc[fr][fc][rr]*inv_s;
      }
    }
  }
}

// ---------------------------------------------------------------------------
// Scan: 256 independent complex recurrences (block-diag 2x2 rotations).
// 3-phase exact chunked scan, NC_=256 chunks of 32.  v is in the y-region of
// d_out (already /scale).  Reference emits carry BEFORE consuming v[t].
// ---------------------------------------------------------------------------
__global__ void scan_a(const float* __restrict__ v, const float* __restrict__ rho_raw,
                       const float* __restrict__ theta, const float* __restrict__ sig8,
                       float* __restrict__ Ssum)
{
  int b = blockIdx.x >> 8, c = blockIdx.x & 255;
  int p = threadIdx.x;
  float sc  = scale_from(sig8);
  float rho = sigmoidf_(rho_raw[p]) * 0.999f / sc;
  float th  = theta[p];
  float ar = rho*cosf(th), ai = rho*sinf(th);
  const float2* vp = (const float2*)v + (b*T_ + c*LCH_)*64 + p;
  float zx=0.f, zy=0.f;
  #pragma unroll 8
  for (int t=0; t<LCH_; ++t){
    float2 vt = vp[t*64];
    float nx = fmaf(ar, zx, fmaf(-ai, zy, vt.x));
    float ny = fmaf(ai, zx, fmaf( ar, zy, vt.y));
    zx = nx; zy = ny;
  }
  ((float2*)Ssum)[(b*NC_ + c)*64 + p] = make_float2(zx, zy);
}

__global__ void scan_b(const float* __restrict__ Ssum, float* __restrict__ Zst,
                       const float* __restrict__ rho_raw, const float* __restrict__ theta,
                       const float* __restrict__ sig8)
{
  int tid = threadIdx.x;          // 256 = B_*64
  int b = tid >> 6, p = tid & 63;
  float sc  = scale_from(sig8);
  float rho = sigmoidf_(rho_raw[p]) * 0.999f / sc;
  float th  = theta[p];
  float qr = rho*cosf(th), qi = rho*sinf(th);
  #pragma unroll
  for (int s=0;s<5;s++){ float nr = qr*qr - qi*qi; float ni = 2.f*qr*qi; qr=nr; qi=ni; } // a^32
  float Zx=0.f, Zy=0.f;
  const float2* S = (const float2*)Ssum;
  float2* Z = (float2*)Zst;
  #pragma unroll 4
  for (int c=0;c<NC_;c++){
    Z[(b*NC_+c)*64 + p] = make_float2(Zx, Zy);
    float2 s = S[(b*NC_+c)*64 + p];
    float nx = qr*Zx - qi*Zy + s.x;
    float ny = qi*Zx + qr*Zy + s.y;
    Zx = nx; Zy = ny;
  }
}

__global__ void scan_c(const float* __restrict__ v, const float* __restrict__ Zst,
                       const float* __restrict__ rho_raw, const float* __restrict__ theta,
                       const float* __restrict__ sig8, float* __restrict__ zout)
{
  int b = blockIdx.x >> 8, c = blockIdx.x & 255;
  int p = threadIdx.x;
  float sc  = scale_from(sig8);
  float rho = sigmoidf_(rho_raw[p]) * 0.999f / sc;
  float th  = theta[p];
  float ar = rho*cosf(th), ai = rho*sinf(th);
  const float2* vp = (const float2*)v + (b*T_ + c*LCH_)*64 + p;
  float2*       zp = (float2*)zout    + (b*T_ + c*LCH_)*64 + p;
  float2 z0 = ((const float2*)Zst)[(b*NC_+c)*64 + p];
  float zx = z0.x, zy = z0.y;
  #pragma unroll 8
  for (int t=0; t<LCH_; ++t){
    zp[t*64] = make_float2(zx, zy);      // emit BEFORE consuming v[t]
    float2 vt = vp[t*64];
    float nx = fmaf(ar, zx, fmaf(-ai, zy, vt.x));
    float ny = fmaf(ai, zx, fmaf( ar, zy, vt.y));
    zx = nx; zy = ny;
  }
}

// ---------------------------------------------------------------------------
extern "C" void kernel_launch(void* const* d_in, const int* in_sizes, int n_in,
                              void* d_out, int out_size, void* d_ws, size_t ws_size,
                              hipStream_t stream)
{
  const float* u       = (const float*)d_in[0];
  const float* rho_raw = (const float*)d_in[1];
  const float* theta   = (const float*)d_in[2];
  const float* K12     = (const float*)d_in[3];
  const float* K21     = (const float*)d_in[4];
  const float* K22     = (const float*)d_in[5];
  const float* gate_w  = (const float*)d_in[6];
  const float* gate_b  = (const float*)d_in[7];
  float* out = (float*)d_out;
  char*  ws  = (char*)d_ws;
  float* sig8 = (float*)ws;
  float* pi   = (float*)(ws + WS_PI);
  unsigned short* w12 = (unsigned short*)(ws + WS_W12);
  unsigned short* w2  = (unsigned short*)(ws + WS_W2);
  float* Ssum = (float*)(ws + WS_S);
  float* Zst  = (float*)(ws + WS_ZST);
  float* v    = out;            // y-region doubles as v scratch until GEMM2
  float* zout = out + Z_OFF;

  hipLaunchKernelGGL(sigma_kernel, dim3(8), dim3(512), 0, stream,
                     rho_raw, theta, K12, K21, K22, sig8);
  hipLaunchKernelGGL(prep_kernel, dim3(BT_/4 + 384), dim3(256), 0, stream,
                     u, gate_w, gate_b, K12, K21, K22, pi, w12, w2);
  hipLaunchKernelGGL((gemm_kernel<1024,false>), dim3(256), dim3(256), 0, stream,
                     u, u, pi, w12, v, sig8);
  hipLaunchKernelGGL(scan_a, dim3(B_*NC_), dim3(64), 0, stream, v, rho_raw, theta, sig8, Ssum);
  hipLaunchKernelGGL(scan_b, dim3(1), dim3(256), 0, stream, Ssum, Zst, rho_raw, theta, sig8);
  hipLaunchKernelGGL(scan_c, dim3(B_*NC_), dim3(64), 0, stream, v, Zst, rho_raw, theta, sig8, zout);
  hipLaunchKernelGGL((gemm_kernel<2048,true>), dim3(256), dim3(256), 0, stream,
                     u, zout, pi, w2, out, sig8);
}